// Round 1
// baseline (1501.340 us; speedup 1.0000x reference)
//
#include <hip/hip_runtime.h>
#include <math.h>

#define NB 2048
#define STAGE_SZ (NB * 16 * 2 * 32)  // 2,097,152 floats per p-mean stage

__device__ __forceinline__ float fast_tanh(float x) {
    float ax = fabsf(x);
    float e  = __expf(2.0f * ax);
    float t  = 1.0f - 2.0f / (e + 1.0f);
    return copysignf(t, x);
}

// ---------------------------------------------------------------------------
// p-stream: per walker, all 256 (i,j) pairs; chain p_v through pW0 + 4 residual
// layers, emitting spin-means over i (stage s used by s-layer s).
// pmeans layout: (5, B, 16(j), 2(h), 32)
// ---------------------------------------------------------------------------
__global__ __launch_bounds__(256) void k_pstream(
    const float* __restrict__ r,
    const float* __restrict__ pW0, const float* __restrict__ pb0,
    const float* __restrict__ pW,  const float* __restrict__ pb,
    float* __restrict__ pmeans)
{
    const int b   = blockIdx.x;
    const int tid = threadIdx.x;
    const int i   = tid & 15;   // first index of p_v (reduced over)
    const int j   = tid >> 4;   // second index (kept)
    __shared__ float rl[48];
    if (tid < 48) rl[tid] = r[b * 48 + tid];
    __syncthreads();

    // rr[b,i,j] = r[b,j] - r[b,i]; eye adds 1 to each comp on diagonal (len only)
    float dx = rl[j * 3 + 0] - rl[i * 3 + 0];
    float dy = rl[j * 3 + 1] - rl[i * 3 + 1];
    float dz = rl[j * 3 + 2] - rl[i * 3 + 2];
    float ee = (i == j) ? 1.0f : 0.0f;
    float len = sqrtf((dx + ee) * (dx + ee) + (dy + ee) * (dy + ee) + (dz + ee) * (dz + ee));

    float p[32];
#pragma unroll
    for (int k = 0; k < 32; ++k) {
        float acc = pb0[k];
        acc += dx  * pW0[0 * 32 + k];
        acc += dy  * pW0[1 * 32 + k];
        acc += dz  * pW0[2 * 32 + k];
        acc += len * pW0[3 * 32 + k];
        p[k] = fast_tanh(acc);
    }
    // stage 0 means (p after pW0)
#pragma unroll
    for (int k = 0; k < 32; ++k) {
        float v = p[k];
        v += __shfl_xor(v, 1);
        v += __shfl_xor(v, 2);
        v += __shfl_xor(v, 4);
        if ((i & 7) == 0)
            pmeans[(size_t)0 * STAGE_SZ + (size_t)((b * 16 + j) * 2 + (i >> 3)) * 32 + k] = v * 0.125f;
    }
    for (int l = 0; l < 4; ++l) {
        const float* Wl = pW + l * 1024;
        const float* bl = pb + l * 32;
        float pn[32];
#pragma unroll
        for (int k = 0; k < 32; ++k) {
            float acc = bl[k];
#pragma unroll
            for (int m = 0; m < 32; ++m) acc += p[m] * Wl[m * 32 + k];
            pn[k] = fast_tanh(acc) + p[k];
        }
#pragma unroll
        for (int k = 0; k < 32; ++k) {
            p[k] = pn[k];
            float v = p[k];
            v += __shfl_xor(v, 1);
            v += __shfl_xor(v, 2);
            v += __shfl_xor(v, 4);
            if ((i & 7) == 0)
                pmeans[(size_t)(l + 1) * STAGE_SZ + (size_t)((b * 16 + j) * 2 + (i >> 3)) * 32 + k] = v * 0.125f;
        }
    }
}

// ---------------------------------------------------------------------------
// Layer 0: build s_emb / p_emb means in-block, blk0 (16x56), s_v1 = tanh(blk0@sW0+sb0)
// writes s_v (B,16,256) and smean (B,2,256)
// ---------------------------------------------------------------------------
__global__ __launch_bounds__(256) void k_s0(
    const float* __restrict__ r, const float* __restrict__ a,
    const float* __restrict__ sW0, const float* __restrict__ sb0,
    float* __restrict__ s_v, float* __restrict__ smean)
{
    const int b   = blockIdx.x;
    const int tid = threadIdx.x;
    __shared__ float rl[48];
    __shared__ float al[12];
    __shared__ float pin[16][16][4];  // [j][i][4] = p_v[b,i,j,:]
    __shared__ float se[16][16];      // s_emb
    __shared__ float sm0[2][16];
    __shared__ float pm0[16][2][4];
    __shared__ float blk[16][56];

    if (tid < 48) rl[tid] = r[b * 48 + tid];
    if (tid >= 64 && tid < 76) al[tid - 64] = a[tid - 64];
    __syncthreads();
    {
        const int i = tid & 15, j = tid >> 4;
        float dx = rl[j * 3 + 0] - rl[i * 3 + 0];
        float dy = rl[j * 3 + 1] - rl[i * 3 + 1];
        float dz = rl[j * 3 + 2] - rl[i * 3 + 2];
        float ee = (i == j) ? 1.0f : 0.0f;
        float len = sqrtf((dx + ee) * (dx + ee) + (dy + ee) * (dy + ee) + (dz + ee) * (dz + ee));
        pin[j][i][0] = dx; pin[j][i][1] = dy; pin[j][i][2] = dz; pin[j][i][3] = len;
    }
    if (tid < 16) {
        const int e = tid;
#pragma unroll
        for (int at = 0; at < 4; ++at) {
            float dx = rl[e * 3 + 0] - al[at * 3 + 0];
            float dy = rl[e * 3 + 1] - al[at * 3 + 1];
            float dz = rl[e * 3 + 2] - al[at * 3 + 2];
            float ln = sqrtf(dx * dx + dy * dy + dz * dz);
            se[e][at * 4 + 0] = dx; se[e][at * 4 + 1] = dy;
            se[e][at * 4 + 2] = dz; se[e][at * 4 + 3] = ln;
        }
    }
    __syncthreads();
    if (tid < 32) {
        const int h = tid >> 4, f = tid & 15;
        float s = 0.f;
        for (int e = 0; e < 8; ++e) s += se[h * 8 + e][f];
        sm0[h][f] = s * 0.125f;
    }
    if (tid < 128) {
        const int j = tid >> 3, h = (tid >> 2) & 1, f = tid & 3;
        float s = 0.f;
        for (int i2 = 0; i2 < 8; ++i2) s += pin[j][h * 8 + i2][f];
        pm0[j][h][f] = s * 0.125f;
    }
    __syncthreads();
    for (int t = tid; t < 16 * 56; t += 256) {
        const int e = t / 56, k = t % 56;
        float v;
        if (k < 16)      v = se[e][k];
        else if (k < 32) v = sm0[0][k - 16];
        else if (k < 48) v = sm0[1][k - 32];
        else if (k < 52) v = pm0[e][0][k - 48];
        else             v = pm0[e][1][k - 52];
        blk[e][k] = v;
    }
    __syncthreads();

    const int n = tid;
    float acc[16];
#pragma unroll
    for (int e = 0; e < 16; ++e) acc[e] = sb0[n];
    for (int k = 0; k < 56; k += 4) {
        float w0 = sW0[(k + 0) * 256 + n];
        float w1 = sW0[(k + 1) * 256 + n];
        float w2 = sW0[(k + 2) * 256 + n];
        float w3 = sW0[(k + 3) * 256 + n];
#pragma unroll
        for (int e = 0; e < 16; ++e) {
            float4 s4 = *(const float4*)&blk[e][k];
            acc[e] += s4.x * w0 + s4.y * w1 + s4.z * w2 + s4.w * w3;
        }
    }
    float* sv_b = s_v + (size_t)b * 4096;
    float mu = 0.f, md = 0.f;
#pragma unroll
    for (int e = 0; e < 16; ++e) {
        float v = fast_tanh(acc[e]);
        sv_b[e * 256 + n] = v;
        if (e < 8) mu += v; else md += v;
    }
    smean[(size_t)b * 512 + n]       = mu * 0.125f;
    smean[(size_t)b * 512 + 256 + n] = md * 0.125f;
}

// ---------------------------------------------------------------------------
// Residual / output s-layer. Decomposed blk @ W:
//   W rows [0,256)=s, [256,512)=mu, [512,768)=md, [768,800)=pu, [800,832)=pd
// block = 1 walker, 128 threads, 2 adjacent cols/thread.
// ---------------------------------------------------------------------------
__global__ __launch_bounds__(128) void k_slayer(
    const float* __restrict__ W, const float* __restrict__ bias,
    const float* __restrict__ pstage,  // (B,16,2,32) for this layer
    float* __restrict__ s_v, float* __restrict__ smean,
    int residual, int write_means)
{
    const int b   = blockIdx.x;
    const int tid = threadIdx.x;
    __shared__ float sOld[16][256];
    __shared__ float mumd[2][256];
    __shared__ float pupd[16][2][32];

    const float* sv_b = s_v + (size_t)b * 4096;
    float* sv_bw      = s_v + (size_t)b * 4096;
    const float* sm_b = smean + (size_t)b * 512;
    const float* ps_b = pstage + (size_t)b * 1024;

    float* sOldF = &sOld[0][0];
    float* mumdF = &mumd[0][0];
    float* pupdF = &pupd[0][0][0];
    for (int t = tid * 4; t < 4096; t += 512)
        *(float4*)&sOldF[t] = *(const float4*)&sv_b[t];
    {
        int t = tid * 4;
        *(float4*)&mumdF[t] = *(const float4*)&sm_b[t];
    }
    for (int t = tid * 4; t < 1024; t += 512)
        *(float4*)&pupdF[t] = *(const float4*)&ps_b[t];
    __syncthreads();

    const int n0 = tid * 2;
    // shared (row-constant) part: bias + mu@W2 + md@W3
    float sh0 = bias[n0], sh1 = bias[n0 + 1];
    for (int k = 0; k < 256; k += 4) {
        float4 mu4 = *(const float4*)&mumd[0][k];
        float4 md4 = *(const float4*)&mumd[1][k];
        float2 a0 = *(const float2*)&W[(256 + k + 0) * 256 + n0];
        float2 a1 = *(const float2*)&W[(256 + k + 1) * 256 + n0];
        float2 a2 = *(const float2*)&W[(256 + k + 2) * 256 + n0];
        float2 a3 = *(const float2*)&W[(256 + k + 3) * 256 + n0];
        float2 c0 = *(const float2*)&W[(512 + k + 0) * 256 + n0];
        float2 c1 = *(const float2*)&W[(512 + k + 1) * 256 + n0];
        float2 c2 = *(const float2*)&W[(512 + k + 2) * 256 + n0];
        float2 c3 = *(const float2*)&W[(512 + k + 3) * 256 + n0];
        sh0 += mu4.x * a0.x + mu4.y * a1.x + mu4.z * a2.x + mu4.w * a3.x
             + md4.x * c0.x + md4.y * c1.x + md4.z * c2.x + md4.w * c3.x;
        sh1 += mu4.x * a0.y + mu4.y * a1.y + mu4.z * a2.y + mu4.w * a3.y
             + md4.x * c0.y + md4.y * c1.y + md4.z * c2.y + md4.w * c3.y;
    }

    float acc0[16], acc1[16];
#pragma unroll
    for (int e = 0; e < 16; ++e) { acc0[e] = 0.f; acc1[e] = 0.f; }
    // s part
    for (int k = 0; k < 256; k += 4) {
        float2 w0 = *(const float2*)&W[(k + 0) * 256 + n0];
        float2 w1 = *(const float2*)&W[(k + 1) * 256 + n0];
        float2 w2 = *(const float2*)&W[(k + 2) * 256 + n0];
        float2 w3 = *(const float2*)&W[(k + 3) * 256 + n0];
#pragma unroll
        for (int e = 0; e < 16; ++e) {
            float4 s4 = *(const float4*)&sOld[e][k];
            acc0[e] += s4.x * w0.x + s4.y * w1.x + s4.z * w2.x + s4.w * w3.x;
            acc1[e] += s4.x * w0.y + s4.y * w1.y + s4.z * w2.y + s4.w * w3.y;
        }
    }
    // pu/pd part
    for (int k = 0; k < 32; k += 4) {
        float2 u0 = *(const float2*)&W[(768 + k + 0) * 256 + n0];
        float2 u1 = *(const float2*)&W[(768 + k + 1) * 256 + n0];
        float2 u2 = *(const float2*)&W[(768 + k + 2) * 256 + n0];
        float2 u3 = *(const float2*)&W[(768 + k + 3) * 256 + n0];
        float2 d0 = *(const float2*)&W[(800 + k + 0) * 256 + n0];
        float2 d1 = *(const float2*)&W[(800 + k + 1) * 256 + n0];
        float2 d2 = *(const float2*)&W[(800 + k + 2) * 256 + n0];
        float2 d3 = *(const float2*)&W[(800 + k + 3) * 256 + n0];
#pragma unroll
        for (int e = 0; e < 16; ++e) {
            float4 pu4 = *(const float4*)&pupd[e][0][k];
            float4 pd4 = *(const float4*)&pupd[e][1][k];
            acc0[e] += pu4.x * u0.x + pu4.y * u1.x + pu4.z * u2.x + pu4.w * u3.x
                     + pd4.x * d0.x + pd4.y * d1.x + pd4.z * d2.x + pd4.w * d3.x;
            acc1[e] += pu4.x * u0.y + pu4.y * u1.y + pu4.z * u2.y + pu4.w * u3.y
                     + pd4.x * d0.y + pd4.y * d1.y + pd4.z * d2.y + pd4.w * d3.y;
        }
    }

    float mu0 = 0.f, mu1 = 0.f, md0 = 0.f, md1 = 0.f;
#pragma unroll
    for (int e = 0; e < 16; ++e) {
        float v0 = fast_tanh(acc0[e] + sh0);
        float v1 = fast_tanh(acc1[e] + sh1);
        if (residual) { v0 += sOld[e][n0]; v1 += sOld[e][n0 + 1]; }
        *(float2*)&sv_bw[e * 256 + n0] = make_float2(v0, v1);
        if (e < 8) { mu0 += v0; mu1 += v1; } else { md0 += v0; md1 += v1; }
    }
    if (write_means) {
        float* smw = smean + (size_t)b * 512;
        smw[n0]           = mu0 * 0.125f;
        smw[n0 + 1]       = mu1 * 0.125f;
        smw[256 + n0]     = md0 * 0.125f;
        smw[256 + n0 + 1] = md1 * 0.125f;
    }
}

// ---------------------------------------------------------------------------
// Orbitals: sw = s_final[:,spin] @ W + b, * env; write orb (B,2,16(det),8(j),8(i))
// ---------------------------------------------------------------------------
__global__ __launch_bounds__(256) void k_orb(
    const float* __restrict__ r, const float* __restrict__ a,
    const float* __restrict__ s_v,
    const float* __restrict__ wuW, const float* __restrict__ wub,
    const float* __restrict__ wdW, const float* __restrict__ wdb,
    float* __restrict__ orb)
{
    const int b   = blockIdx.x;
    const int tid = threadIdx.x;
    __shared__ float sF[16][256];
    __shared__ float envl[16];
    const float* sv_b = s_v + (size_t)b * 4096;
    float* sFF = &sF[0][0];
    for (int t = tid * 4; t < 4096; t += 1024)
        *(float4*)&sFF[t] = *(const float4*)&sv_b[t];
    if (tid < 16) {
        float ex = 0.f;
#pragma unroll
        for (int at = 0; at < 4; ++at) {
            float dx = r[b * 48 + tid * 3 + 0] - a[at * 3 + 0];
            float dy = r[b * 48 + tid * 3 + 1] - a[at * 3 + 1];
            float dz = r[b * 48 + tid * 3 + 2] - a[at * 3 + 2];
            ex += __expf(-sqrtf(dx * dx + dy * dy + dz * dz));
        }
        envl[tid] = ex;
    }
    __syncthreads();

    const int spin = tid >> 7;
    const int c    = tid & 127;
    const float* Wm = spin ? wdW : wuW;
    const float* bm = spin ? wdb : wub;
    const int e0 = spin * 8;
    float acc[8];
    const float bias = bm[c];
#pragma unroll
    for (int e = 0; e < 8; ++e) acc[e] = bias;
    for (int k = 0; k < 256; k += 4) {
        float w0 = Wm[(k + 0) * 128 + c];
        float w1 = Wm[(k + 1) * 128 + c];
        float w2 = Wm[(k + 2) * 128 + c];
        float w3 = Wm[(k + 3) * 128 + c];
#pragma unroll
        for (int e = 0; e < 8; ++e) {
            float4 s4 = *(const float4*)&sF[e0 + e][k];
            acc[e] += s4.x * w0 + s4.y * w1 + s4.z * w2 + s4.w * w3;
        }
    }
    const int d = c & 15, jrow = c >> 4;
    float out[8];
#pragma unroll
    for (int e = 0; e < 8; ++e) out[e] = acc[e] * envl[e0 + e];
    float* dst = orb + ((size_t)((b * 2 + spin) * 16 + d) * 8 + jrow) * 8;
    *(float4*)dst       = make_float4(out[0], out[1], out[2], out[3]);
    *(float4*)(dst + 4) = make_float4(out[4], out[5], out[6], out[7]);
}

// ---------------------------------------------------------------------------
// slogdet of 8x8 (partial pivoting, fully unrolled) + det-combine + logsumexp
// ---------------------------------------------------------------------------
__device__ __forceinline__ void slogdet8(float M[8][8], float& sgn_out, float& ld_out) {
    float sgn = 1.f, ld = 0.f;
#pragma unroll
    for (int k = 0; k < 8; ++k) {
        float best = fabsf(M[k][k]);
        int p = k;
#pragma unroll
        for (int rr = k + 1; rr < 8; ++rr) {
            float v = fabsf(M[rr][k]);
            if (v > best) { best = v; p = rr; }
        }
        if (p != k) sgn = -sgn;
#pragma unroll
        for (int rr = k + 1; rr < 8; ++rr) {
            bool sw = (rr == p);
#pragma unroll
            for (int cc = k; cc < 8; ++cc) {
                float x = M[k][cc], y = M[rr][cc];
                M[k][cc]  = sw ? y : x;
                M[rr][cc] = sw ? x : y;
            }
        }
        float piv = M[k][k];
        if (piv < 0.f) sgn = -sgn;
        ld += logf(fabsf(piv));
        float inv = 1.f / piv;
#pragma unroll
        for (int rr = k + 1; rr < 8; ++rr) {
            float f = M[rr][k] * inv;
#pragma unroll
            for (int cc = k + 1; cc < 8; ++cc) M[rr][cc] -= f * M[k][cc];
        }
    }
    sgn_out = sgn; ld_out = ld;
}

__global__ __launch_bounds__(256) void k_det(
    const float* __restrict__ orb, const float* __restrict__ wfW,
    float* __restrict__ out)
{
    const int g = blockIdx.x * 256 + threadIdx.x;
    const int b = g >> 4, d = g & 15;
    float M[8][8];
    const float* src = orb + (size_t)((b * 2 + 0) * 16 + d) * 64;
#pragma unroll
    for (int rr = 0; rr < 8; ++rr) {
        float4 v0 = *(const float4*)&src[rr * 8];
        float4 v1 = *(const float4*)&src[rr * 8 + 4];
        M[rr][0] = v0.x; M[rr][1] = v0.y; M[rr][2] = v0.z; M[rr][3] = v0.w;
        M[rr][4] = v1.x; M[rr][5] = v1.y; M[rr][6] = v1.z; M[rr][7] = v1.w;
    }
    float s1, l1; slogdet8(M, s1, l1);
    src = orb + (size_t)((b * 2 + 1) * 16 + d) * 64;
#pragma unroll
    for (int rr = 0; rr < 8; ++rr) {
        float4 v0 = *(const float4*)&src[rr * 8];
        float4 v1 = *(const float4*)&src[rr * 8 + 4];
        M[rr][0] = v0.x; M[rr][1] = v0.y; M[rr][2] = v0.z; M[rr][3] = v0.w;
        M[rr][4] = v1.x; M[rr][5] = v1.y; M[rr][6] = v1.z; M[rr][7] = v1.w;
    }
    float s2, l2; slogdet8(M, s2, l2);
    float sgn = s1 * s2;
    float ld  = l1 + l2;

    float m = ld;
    m = fmaxf(m, __shfl_xor(m, 1));
    m = fmaxf(m, __shfl_xor(m, 2));
    m = fmaxf(m, __shfl_xor(m, 4));
    m = fmaxf(m, __shfl_xor(m, 8));
    float sub = sgn * __expf(ld - m) * wfW[d];
    sub += __shfl_xor(sub, 1);
    sub += __shfl_xor(sub, 2);
    sub += __shfl_xor(sub, 4);
    sub += __shfl_xor(sub, 8);
    if (d == 0) out[b] = logf(fabsf(sub)) + m;
}

// ---------------------------------------------------------------------------
extern "C" void kernel_launch(void* const* d_in, const int* in_sizes, int n_in,
                              void* d_out, int out_size, void* d_ws, size_t ws_size,
                              hipStream_t stream) {
    (void)in_sizes; (void)n_in; (void)out_size; (void)ws_size;
    const float* r   = (const float*)d_in[0];
    const float* a   = (const float*)d_in[1];
    const float* sW0 = (const float*)d_in[2];
    const float* sb0 = (const float*)d_in[3];
    const float* sW  = (const float*)d_in[4];
    const float* sb  = (const float*)d_in[5];
    const float* pW0 = (const float*)d_in[6];
    const float* pb0 = (const float*)d_in[7];
    const float* pW  = (const float*)d_in[8];
    const float* pb  = (const float*)d_in[9];
    const float* vW  = (const float*)d_in[10];
    const float* vb  = (const float*)d_in[11];
    const float* wuW = (const float*)d_in[12];
    const float* wub = (const float*)d_in[13];
    const float* wdW = (const float*)d_in[14];
    const float* wdb = (const float*)d_in[15];
    const float* wfW = (const float*)d_in[16];
    float* out = (float*)d_out;

    float* ws     = (float*)d_ws;
    float* pmeans = ws;                          // 5 * 2,097,152 = 10,485,760 floats
    float* s_v    = ws + (size_t)5 * STAGE_SZ;   // 8,388,608 floats
    float* smean  = s_v + (size_t)NB * 4096;     // 1,048,576 floats
    float* orb    = pmeans;                      // alias: stages 0-1 dead by k_orb time

    k_pstream<<<NB, 256, 0, stream>>>(r, pW0, pb0, pW, pb, pmeans);
    k_s0<<<NB, 256, 0, stream>>>(r, a, sW0, sb0, s_v, smean);
    for (int l = 0; l < 4; ++l) {
        k_slayer<<<NB, 128, 0, stream>>>(sW + (size_t)l * 832 * 256, sb + l * 256,
                                         pmeans + (size_t)l * STAGE_SZ,
                                         s_v, smean, 1, 1);
    }
    k_slayer<<<NB, 128, 0, stream>>>(vW, vb, pmeans + (size_t)4 * STAGE_SZ,
                                     s_v, smean, 0, 0);
    k_orb<<<NB, 256, 0, stream>>>(r, a, s_v, wuW, wub, wdW, wdb, orb);
    k_det<<<NB / 16, 256, 0, stream>>>(orb, wfW, out);
}